// Round 1
// baseline (583.454 us; speedup 1.0000x reference)
//
#include <hip/hip_runtime.h>
#include <stdint.h>

#define HID 1024
#define NH 16
#define DH 64
#define NB 4
#define SQL 1024
#define MROWS (NB*SQL)   // 4096

typedef unsigned short u16;
typedef __attribute__((ext_vector_type(8))) short short8;
typedef __attribute__((ext_vector_type(4))) float f32x4;

__device__ __forceinline__ u16 f2bf(float f){
  union { float f; uint32_t u; } v; v.f = f;
  uint32_t u = v.u;
  u += 0x7FFF + ((u >> 16) & 1);   // RNE
  return (u16)(u >> 16);
}

__device__ __forceinline__ void gld_lds16(const u16* g, u16* l){
  __builtin_amdgcn_global_load_lds((const __attribute__((address_space(1))) void*)g,
                                   (__attribute__((address_space(3))) void*)l, 16, 0, 0);
}

// ---------------- fp32 -> bf16 convert ----------------
__global__ __launch_bounds__(256) void cvt_bf16(const float* __restrict__ in,
                                                u16* __restrict__ out, int n){
  int idx = (blockIdx.x*256 + threadIdx.x)*4;
  if (idx < n){
    float4 f = *(const float4*)(in + idx);
    u16 o0=f2bf(f.x), o1=f2bf(f.y), o2=f2bf(f.z), o3=f2bf(f.w);
    ushort4 o; o.x=o0; o.y=o1; o.z=o2; o.w=o3;
    *(ushort4*)(out+idx) = o;
  }
}

// ---------------- W [K][N] fp32 -> Wt [N][K] bf16 ----------------
__global__ __launch_bounds__(256) void transpose_w(const float* __restrict__ W,
                                                   u16* __restrict__ Wt){
  __shared__ __align__(16) u16 tile[64][65];
  const int t = threadIdx.x;
  const int r0 = blockIdx.y*64, c0 = blockIdx.x*64;
  #pragma unroll
  for (int i=0;i<16;i++){
    int idx = i*256 + t; int r = idx>>6, c = idx&63;
    tile[r][c] = f2bf(W[(size_t)(r0+r)*HID + c0 + c]);
  }
  __syncthreads();
  #pragma unroll
  for (int i=0;i<16;i++){
    int idx = i*256 + t; int n = idx>>6, k = idx&63;
    Wt[(size_t)(c0+n)*HID + r0 + k] = tile[k][n];
  }
}

// ---------------- GEMM: C[M=4096][N=1024] = A[M][K=1024] * Bt[N][K]^T + bias[n]
// MODE 0: out bf16 head-layout [B,H,S,D]   (Q/K projections)
// MODE 1: out bf16 Vt layout  [B,H,D,S]    (V projection)
// MODE 2: out fp32 [M][N]                  (final projection)
template<int MODE>
__global__ __launch_bounds__(256) void gemm_bt(const u16* __restrict__ A,
    const u16* __restrict__ Bt, const float* __restrict__ bias,
    void* __restrict__ outp){
  __shared__ __align__(16) u16 As[128*64];
  __shared__ __align__(16) u16 Bs[128*64];
  const int t = threadIdx.x;
  const int n0 = blockIdx.x*128, m0 = blockIdx.y*128;
  const int w = t>>6, lane = t&63, lr = lane&15, lhi = lane>>4;
  const int wr = w>>1, wc = w&1;
  const int K = HID;

  f32x4 acc[4][4];
  #pragma unroll
  for (int i=0;i<4;i++)
    #pragma unroll
    for (int j=0;j<4;j++) acc[i][j] = 0.0f;

  for (int kt=0; kt<K/64; ++kt){
    __syncthreads();
    const u16* Ag = A + (size_t)m0*K + kt*64;
    const u16* Bg = Bt + (size_t)n0*K + kt*64;
    #pragma unroll
    for (int i=0;i<4;i++){
      int seg = i*256 + t;
      gld_lds16(Ag + (seg>>3)*K + (seg&7)*8, As + seg*8);
    }
    #pragma unroll
    for (int i=0;i<4;i++){
      int seg = i*256 + t;
      gld_lds16(Bg + (seg>>3)*K + (seg&7)*8, Bs + seg*8);
    }
    __syncthreads();
    #pragma unroll
    for (int sl=0; sl<2; ++sl){
      short8 af[4], bf[4];
      #pragma unroll
      for (int mi=0;mi<4;mi++)
        af[mi] = *(const short8*)(As + (wr*64 + mi*16 + lr)*64 + sl*32 + lhi*8);
      #pragma unroll
      for (int ni=0;ni<4;ni++)
        bf[ni] = *(const short8*)(Bs + (wc*64 + ni*16 + lr)*64 + sl*32 + lhi*8);
      #pragma unroll
      for (int mi=0;mi<4;mi++)
        #pragma unroll
        for (int ni=0;ni<4;ni++)
          acc[mi][ni] = __builtin_amdgcn_mfma_f32_16x16x32_bf16(af[mi], bf[ni], acc[mi][ni], 0,0,0);
    }
  }

  #pragma unroll
  for (int mi=0;mi<4;mi++){
    #pragma unroll
    for (int ni=0;ni<4;ni++){
      const int n = n0 + wc*64 + ni*16 + lr;
      const int mbase = m0 + wr*64 + mi*16 + lhi*4;
      const float bv = bias[n];
      #pragma unroll
      for (int r=0;r<4;r++){
        const int m = mbase + r;
        float val = acc[mi][ni][r] + bv;
        if (MODE == 2){
          ((float*)outp)[(size_t)m*HID + n] = val;
        } else {
          int b = m >> 10, s = m & 1023;
          int h = n >> 6,  d = n & 63;
          if (MODE == 0)
            ((u16*)outp)[(((size_t)(b*NH + h))*SQL + s)*DH + d] = f2bf(val);
          else
            ((u16*)outp)[(((size_t)(b*NH + h))*DH + d)*SQL + s] = f2bf(val);
        }
      }
    }
  }
}

// ---------------- fused flash attention ----------------
// grid (S/64, B*H), 256 threads (4 waves, each owns 16 q-rows)
__global__ __launch_bounds__(256) void attn_fwd(const u16* __restrict__ Qh,
    const u16* __restrict__ Kh, const u16* __restrict__ Vt,
    const float* __restrict__ bias, u16* __restrict__ ctx){
  __shared__ __align__(16) u16 Ks[64*64];
  __shared__ __align__(16) u16 Vs[64*64];
  __shared__ __align__(16) u16 Ps[4*16*64];
  const int t = threadIdx.x, w = t>>6, lane = t&63, lr = lane&15, lhi = lane>>4;
  const int q0 = blockIdx.x*64;
  const int bh = blockIdx.y;
  const int b = bh >> 4, h = bh & 15;
  const u16* Qp = Qh + (size_t)bh*SQL*DH;
  const u16* Kp = Kh + (size_t)bh*SQL*DH;
  const u16* Vp = Vt + (size_t)bh*DH*SQL;
  const float* Bp = bias + ((size_t)bh*SQL + q0)*SQL;

  short8 qf[2];
  {
    const int qrow = q0 + w*16 + lr;
    qf[0] = *(const short8*)(Qp + qrow*DH + lhi*8);
    qf[1] = *(const short8*)(Qp + qrow*DH + 32 + lhi*8);
  }

  float m_run[4], l_run[4];
  f32x4 o[4];
  #pragma unroll
  for (int r=0;r<4;r++){ m_run[r] = -3.0e38f; l_run[r] = 0.0f; }
  #pragma unroll
  for (int dg=0;dg<4;dg++) o[dg] = 0.0f;

  for (int kt=0; kt<SQL/64; ++kt){
    __syncthreads();
    #pragma unroll
    for (int i=0;i<2;i++){
      int seg = i*256 + t;
      gld_lds16(Kp + (kt*64 + (seg>>3))*DH + (seg&7)*8, Ks + seg*8);
    }
    #pragma unroll
    for (int i=0;i<2;i++){
      int seg = i*256 + t;
      gld_lds16(Vp + (size_t)(seg>>3)*SQL + kt*64 + (seg&7)*8, Vs + seg*8);
    }
    __syncthreads();

    // S = scale * Q K^T + bias
    f32x4 sa[4];
    #pragma unroll
    for (int n=0;n<4;n++) sa[n] = 0.0f;
    #pragma unroll
    for (int sl=0; sl<2; ++sl){
      #pragma unroll
      for (int n=0;n<4;n++){
        short8 kf = *(const short8*)(Ks + (n*16+lr)*64 + sl*32 + lhi*8);
        sa[n] = __builtin_amdgcn_mfma_f32_16x16x32_bf16(qf[sl], kf, sa[n], 0,0,0);
      }
    }
    float sv[4][4];
    #pragma unroll
    for (int n=0;n<4;n++)
      #pragma unroll
      for (int r=0;r<4;r++){
        float bvv = Bp[(size_t)(w*16 + lhi*4 + r)*SQL + kt*64 + n*16 + lr];
        sv[n][r] = sa[n][r]*0.125f + bvv;
      }

    // online softmax over this 64-key tile
    float tmax[4];
    #pragma unroll
    for (int r=0;r<4;r++)
      tmax[r] = fmaxf(fmaxf(sv[0][r],sv[1][r]), fmaxf(sv[2][r],sv[3][r]));
    #pragma unroll
    for (int off=1; off<16; off<<=1)
      #pragma unroll
      for (int r=0;r<4;r++)
        tmax[r] = fmaxf(tmax[r], __shfl_xor(tmax[r], off, 64));

    float alpha[4], rsum[4];
    #pragma unroll
    for (int r=0;r<4;r++){
      float mnew = fmaxf(m_run[r], tmax[r]);
      alpha[r] = __expf(m_run[r] - mnew);
      m_run[r] = mnew;
      rsum[r] = 0.0f;
    }
    #pragma unroll
    for (int n=0;n<4;n++)
      #pragma unroll
      for (int r=0;r<4;r++){
        float p = __expf(sv[n][r] - m_run[r]);
        sv[n][r] = p;
        rsum[r] += p;
      }
    #pragma unroll
    for (int off=1; off<16; off<<=1)
      #pragma unroll
      for (int r=0;r<4;r++)
        rsum[r] += __shfl_xor(rsum[r], off, 64);
    #pragma unroll
    for (int r=0;r<4;r++) l_run[r] = l_run[r]*alpha[r] + rsum[r];
    #pragma unroll
    for (int dg=0;dg<4;dg++)
      #pragma unroll
      for (int r=0;r<4;r++) o[dg][r] *= alpha[r];

    // P (C-layout) -> wave-private LDS -> A-layout fragments
    u16* Pw = Ps + w*(16*64);
    #pragma unroll
    for (int n=0;n<4;n++)
      #pragma unroll
      for (int r=0;r<4;r++)
        Pw[(lhi*4 + r)*64 + n*16 + lr] = f2bf(sv[n][r]);
    asm volatile("s_waitcnt lgkmcnt(0)" ::: "memory");

    #pragma unroll
    for (int sl=0; sl<2; ++sl){
      short8 pf = *(const short8*)(Pw + lr*64 + sl*32 + lhi*8);
      #pragma unroll
      for (int dg=0; dg<4; dg++){
        short8 vf = *(const short8*)(Vs + (dg*16+lr)*64 + sl*32 + lhi*8);
        o[dg] = __builtin_amdgcn_mfma_f32_16x16x32_bf16(pf, vf, o[dg], 0,0,0);
      }
    }
  }

  // ctx[b][s][h*64+d]  (bf16)
  #pragma unroll
  for (int dg=0; dg<4; dg++)
    #pragma unroll
    for (int r=0;r<4;r++){
      float val = o[dg][r] / l_run[r];
      int srow = q0 + w*16 + lhi*4 + r;
      ctx[((size_t)b*SQL + srow)*HID + h*64 + dg*16 + lr] = f2bf(val);
    }
}

extern "C" void kernel_launch(void* const* d_in, const int* in_sizes, int n_in,
                              void* d_out, int out_size, void* d_ws, size_t ws_size,
                              hipStream_t stream){
  const float* q  = (const float*)d_in[0];
  const float* k  = (const float*)d_in[1];
  const float* v  = (const float*)d_in[2];
  const float* ab = (const float*)d_in[3];
  const float* Wq = (const float*)d_in[4];
  const float* Wk = (const float*)d_in[5];
  const float* Wv = (const float*)d_in[6];
  const float* Wo = (const float*)d_in[7];
  const float* bq = (const float*)d_in[8];
  const float* bk = (const float*)d_in[9];
  const float* bv = (const float*)d_in[10];
  const float* bo = (const float*)d_in[11];

  char* ws = (char*)d_ws;
  const size_t MB = 1024*1024;
  u16* qb  = (u16*)(ws + 0*MB);    // 8 MB  [4096][1024] bf16
  u16* kb  = (u16*)(ws + 8*MB);
  u16* vb  = (u16*)(ws + 16*MB);
  u16* wqt = (u16*)(ws + 24*MB);   // 2 MB each, [N][K] bf16
  u16* wkt = (u16*)(ws + 26*MB);
  u16* wvt = (u16*)(ws + 28*MB);
  u16* wot = (u16*)(ws + 30*MB);
  u16* Qh  = (u16*)(ws + 32*MB);   // [B,H,S,D] bf16
  u16* Kh  = (u16*)(ws + 40*MB);   // [B,H,S,D]
  u16* Vt  = (u16*)(ws + 48*MB);   // [B,H,D,S]
  u16* ctx = (u16*)(ws + 56*MB);   // [B,S,HID] bf16

  const int NEL = MROWS*HID;       // 4194304
  dim3 cb(256), cg(NEL/4/256);
  cvt_bf16<<<cg, cb, 0, stream>>>(q, qb, NEL);
  cvt_bf16<<<cg, cb, 0, stream>>>(k, kb, NEL);
  cvt_bf16<<<cg, cb, 0, stream>>>(v, vb, NEL);

  dim3 tg(16,16);
  transpose_w<<<tg, cb, 0, stream>>>(Wq, wqt);
  transpose_w<<<tg, cb, 0, stream>>>(Wk, wkt);
  transpose_w<<<tg, cb, 0, stream>>>(Wv, wvt);
  transpose_w<<<tg, cb, 0, stream>>>(Wo, wot);

  dim3 gg(HID/128, MROWS/128);     // (8, 32)
  gemm_bt<0><<<gg, cb, 0, stream>>>(qb, wqt, bq, (void*)Qh);
  gemm_bt<0><<<gg, cb, 0, stream>>>(kb, wkt, bk, (void*)Kh);
  gemm_bt<1><<<gg, cb, 0, stream>>>(vb, wvt, bv, (void*)Vt);

  dim3 ag(SQL/64, NB*NH);          // (16, 64)
  attn_fwd<<<ag, cb, 0, stream>>>(Qh, Kh, Vt, ab, ctx);

  gemm_bt<2><<<gg, cb, 0, stream>>>(ctx, wot, bo, d_out);
}

// Round 2
// 558.780 us; speedup vs baseline: 1.0442x; 1.0442x over previous
//
#include <hip/hip_runtime.h>
#include <stdint.h>

#define HID 1024
#define NH 16
#define DH 64
#define NB 4
#define SQL 1024
#define MROWS (NB*SQL)   // 4096

typedef unsigned short u16;
typedef __attribute__((ext_vector_type(8))) short short8;
typedef __attribute__((ext_vector_type(4))) float f32x4;

__device__ __forceinline__ u16 f2bf(float f){
  union { float f; uint32_t u; } v; v.f = f;
  uint32_t u = v.u;
  u += 0x7FFF + ((u >> 16) & 1);   // RNE
  return (u16)(u >> 16);
}

__device__ __forceinline__ void gld_lds16(const u16* g, u16* l){
  __builtin_amdgcn_global_load_lds((const __attribute__((address_space(1))) void*)g,
                                   (__attribute__((address_space(3))) void*)l, 16, 0, 0);
}

// ---------------- fp32 -> bf16 convert (q,k,v fused) ----------------
__global__ __launch_bounds__(256) void cvt_bf16_3(const float* __restrict__ s0,
    const float* __restrict__ s1, const float* __restrict__ s2,
    u16* __restrict__ d0, u16* __restrict__ d1, u16* __restrict__ d2){
  const float* src = (blockIdx.y==0) ? s0 : (blockIdx.y==1) ? s1 : s2;
  u16* dst = (blockIdx.y==0) ? d0 : (blockIdx.y==1) ? d1 : d2;
  int idx = (blockIdx.x*256 + threadIdx.x)*4;
  float4 f = *(const float4*)(src + idx);
  ushort4 o; o.x=f2bf(f.x); o.y=f2bf(f.y); o.z=f2bf(f.z); o.w=f2bf(f.w);
  *(ushort4*)(dst+idx) = o;
}

// ---------------- W [K][N] fp32 -> Wt [N][K] bf16 (4 fused) ----------------
__global__ __launch_bounds__(256) void transpose_w4(
    const float* __restrict__ W0, const float* __restrict__ W1,
    const float* __restrict__ W2, const float* __restrict__ W3,
    u16* __restrict__ T0, u16* __restrict__ T1,
    u16* __restrict__ T2, u16* __restrict__ T3){
  const float* W = (blockIdx.z==0)?W0:(blockIdx.z==1)?W1:(blockIdx.z==2)?W2:W3;
  u16* Wt = (blockIdx.z==0)?T0:(blockIdx.z==1)?T1:(blockIdx.z==2)?T2:T3;
  __shared__ __align__(16) u16 tile[64][65];
  const int t = threadIdx.x;
  const int r0 = blockIdx.y*64, c0 = blockIdx.x*64;
  #pragma unroll
  for (int i=0;i<16;i++){
    int idx = i*256 + t; int r = idx>>6, c = idx&63;
    tile[r][c] = f2bf(W[(size_t)(r0+r)*HID + c0 + c]);
  }
  __syncthreads();
  #pragma unroll
  for (int i=0;i<16;i++){
    int idx = i*256 + t; int n = idx>>6, k = idx&63;
    Wt[(size_t)(c0+n)*HID + r0 + k] = tile[k][n];
  }
}

// ---------------- GEMM core: C[M][N=1024] = A[M][K=1024] * Bt[N][K]^T + bias[n]
// mode 0: out bf16 [B,H,S,D]; mode 1: out bf16 [B,H,D,S]; mode 2: out fp32 [M][N]
__device__ __forceinline__ void gemm_core(const u16* __restrict__ A,
    const u16* __restrict__ Bt, const float* __restrict__ bias,
    void* __restrict__ outp, int mode){
  __shared__ __align__(16) u16 As[2][128*64];
  __shared__ __align__(16) u16 Bs[2][128*64];
  const int t = threadIdx.x;
  const int n0 = blockIdx.x*128, m0 = blockIdx.y*128;
  const int w = t>>6, lane = t&63, lr = lane&15, lhi = lane>>4;
  const int wr = w>>1, wc = w&1;

  f32x4 acc[4][4];
  #pragma unroll
  for (int i=0;i<4;i++)
    #pragma unroll
    for (int j=0;j<4;j++) acc[i][j] = 0.0f;

  const u16* Ag0 = A + (size_t)m0*HID;
  const u16* Bg0 = Bt + (size_t)n0*HID;

  // prologue: stage tile 0
  #pragma unroll
  for (int i=0;i<4;i++){
    int seg = i*256 + t;
    gld_lds16(Ag0 + (size_t)(seg>>3)*HID + (seg&7)*8, &As[0][seg*8]);
  }
  #pragma unroll
  for (int i=0;i<4;i++){
    int seg = i*256 + t;
    gld_lds16(Bg0 + (size_t)(seg>>3)*HID + (seg&7)*8, &Bs[0][seg*8]);
  }
  __syncthreads();

  int cur = 0;
  for (int kt=0; kt<HID/64; ++kt){
    if (kt+1 < HID/64){
      const u16* Ag = Ag0 + (kt+1)*64;
      const u16* Bg = Bg0 + (kt+1)*64;
      #pragma unroll
      for (int i=0;i<4;i++){
        int seg = i*256 + t;
        gld_lds16(Ag + (size_t)(seg>>3)*HID + (seg&7)*8, &As[cur^1][seg*8]);
      }
      #pragma unroll
      for (int i=0;i<4;i++){
        int seg = i*256 + t;
        gld_lds16(Bg + (size_t)(seg>>3)*HID + (seg&7)*8, &Bs[cur^1][seg*8]);
      }
    }
    #pragma unroll
    for (int sl=0; sl<2; ++sl){
      short8 af[4], bf[4];
      #pragma unroll
      for (int mi=0;mi<4;mi++)
        af[mi] = *(const short8*)(&As[cur][(wr*64 + mi*16 + lr)*64 + sl*32 + lhi*8]);
      #pragma unroll
      for (int ni=0;ni<4;ni++)
        bf[ni] = *(const short8*)(&Bs[cur][(wc*64 + ni*16 + lr)*64 + sl*32 + lhi*8]);
      #pragma unroll
      for (int mi=0;mi<4;mi++)
        #pragma unroll
        for (int ni=0;ni<4;ni++)
          acc[mi][ni] = __builtin_amdgcn_mfma_f32_16x16x32_bf16(af[mi], bf[ni], acc[mi][ni], 0,0,0);
    }
    __syncthreads();
    cur ^= 1;
  }

  #pragma unroll
  for (int mi=0;mi<4;mi++){
    #pragma unroll
    for (int ni=0;ni<4;ni++){
      const int n = n0 + wc*64 + ni*16 + lr;
      const int mbase = m0 + wr*64 + mi*16 + lhi*4;
      const float bv = bias[n];
      #pragma unroll
      for (int r=0;r<4;r++){
        const int m = mbase + r;
        float val = acc[mi][ni][r] + bv;
        if (mode == 2){
          ((float*)outp)[(size_t)m*HID + n] = val;
        } else {
          int b = m >> 10, s = m & 1023;
          int h = n >> 6,  d = n & 63;
          if (mode == 0)
            ((u16*)outp)[(((size_t)(b*NH + h))*SQL + s)*DH + d] = f2bf(val);
          else
            ((u16*)outp)[(((size_t)(b*NH + h))*DH + d)*SQL + s] = f2bf(val);
        }
      }
    }
  }
}

__global__ __launch_bounds__(256) void gemm_qkv(
    const u16* __restrict__ qA, const u16* __restrict__ kA, const u16* __restrict__ vA,
    const u16* __restrict__ Wq, const u16* __restrict__ Wk, const u16* __restrict__ Wv,
    const float* __restrict__ bq, const float* __restrict__ bk, const float* __restrict__ bv,
    u16* __restrict__ Qh, u16* __restrict__ Kh, u16* __restrict__ Vt){
  int z = blockIdx.z;
  const u16* A  = (z==0)?qA:(z==1)?kA:vA;
  const u16* Bt = (z==0)?Wq:(z==1)?Wk:Wv;
  const float* bias = (z==0)?bq:(z==1)?bk:bv;
  u16* out = (z==0)?Qh:(z==1)?Kh:Vt;
  gemm_core(A, Bt, bias, (void*)out, (z==2)?1:0);
}

__global__ __launch_bounds__(256) void gemm_o(const u16* __restrict__ A,
    const u16* __restrict__ Bt, const float* __restrict__ bias, float* __restrict__ out){
  gemm_core(A, Bt, bias, (void*)out, 2);
}

// ---------------- fused flash attention ----------------
// grid (S/64, B*H), 256 threads (4 waves, each owns 16 q-rows)
// K/V reg-staged into XOR-swizzled LDS, double-buffered (2-phase).
__global__ __launch_bounds__(256) void attn_fwd(const u16* __restrict__ Qh,
    const u16* __restrict__ Kh, const u16* __restrict__ Vt,
    const float* __restrict__ bias, u16* __restrict__ ctx){
  __shared__ __align__(16) u16 Ks[2][64*64];
  __shared__ __align__(16) u16 Vs[2][64*64];
  __shared__ __align__(16) u16 Ps[4*16*64];
  const int t = threadIdx.x, w = t>>6, lane = t&63, lr = lane&15, lhi = lane>>4;
  const int q0 = blockIdx.x*64;
  const int bh = blockIdx.y;
  const int b = bh >> 4, h = bh & 15;
  const u16* Qp = Qh + (size_t)bh*SQL*DH;
  const u16* Kp = Kh + (size_t)bh*SQL*DH;
  const u16* Vp = Vt + (size_t)bh*DH*SQL;
  const float* Bp = bias + ((size_t)bh*SQL + q0)*SQL;

  // per-thread staging geometry: 2 chunks of 16B for K, 2 for V
  const int srow0 = t>>3,        scol0 = t&7;
  const int srow1 = 32 + (t>>3), scol1 = t&7;
  const int ldso0 = srow0*64 + ((scol0*8) ^ ((srow0&7)<<3));
  const int ldso1 = srow1*64 + ((scol1*8) ^ ((srow1&7)<<3));

  short8 qf[2];
  {
    const int qrow = q0 + w*16 + lr;
    qf[0] = *(const short8*)(Qp + (size_t)qrow*DH + lhi*8);
    qf[1] = *(const short8*)(Qp + (size_t)qrow*DH + 32 + lhi*8);
  }

  float m_run[4], l_run[4];
  f32x4 o[4];
  #pragma unroll
  for (int r=0;r<4;r++){ m_run[r] = -3.0e38f; l_run[r] = 0.0f; }
  #pragma unroll
  for (int dg=0;dg<4;dg++) o[dg] = 0.0f;

  // prologue: stage tile 0
  {
    short8 k0 = *(const short8*)(Kp + (size_t)srow0*DH + scol0*8);
    short8 k1 = *(const short8*)(Kp + (size_t)srow1*DH + scol1*8);
    short8 v0 = *(const short8*)(Vp + (size_t)srow0*SQL + scol0*8);
    short8 v1 = *(const short8*)(Vp + (size_t)srow1*SQL + scol1*8);
    *(short8*)(&Ks[0][ldso0]) = k0;
    *(short8*)(&Ks[0][ldso1]) = k1;
    *(short8*)(&Vs[0][ldso0]) = v0;
    *(short8*)(&Vs[0][ldso1]) = v1;
  }
  __syncthreads();

  int cur = 0;
  for (int kt=0; kt<SQL/64; ++kt){
    // A: issue next tile's global loads early (latency hides under compute)
    short8 kreg0, kreg1, vreg0, vreg1;
    const bool pre = (kt+1 < SQL/64);
    if (pre){
      const int kn = (kt+1)*64;
      kreg0 = *(const short8*)(Kp + (size_t)(kn + srow0)*DH + scol0*8);
      kreg1 = *(const short8*)(Kp + (size_t)(kn + srow1)*DH + scol1*8);
      vreg0 = *(const short8*)(Vp + (size_t)srow0*SQL + kn + scol0*8);
      vreg1 = *(const short8*)(Vp + (size_t)srow1*SQL + kn + scol1*8);
    }

    // B: bias loads for this tile (consumed after QK^T)
    float bvv[4][4];
    #pragma unroll
    for (int n=0;n<4;n++)
      #pragma unroll
      for (int r=0;r<4;r++)
        bvv[n][r] = Bp[(size_t)(w*16 + lhi*4 + r)*SQL + kt*64 + n*16 + lr];

    // C: S = scale * Q K^T  (swizzled K reads)
    f32x4 sa[4];
    #pragma unroll
    for (int n=0;n<4;n++) sa[n] = 0.0f;
    #pragma unroll
    for (int sl=0; sl<2; ++sl){
      const int co = (sl*32 + lhi*8) ^ ((lr&7)<<3);
      #pragma unroll
      for (int n=0;n<4;n++){
        short8 kf = *(const short8*)(&Ks[cur][(n*16+lr)*64 + co]);
        sa[n] = __builtin_amdgcn_mfma_f32_16x16x32_bf16(qf[sl], kf, sa[n], 0,0,0);
      }
    }
    float sv[4][4];
    #pragma unroll
    for (int n=0;n<4;n++)
      #pragma unroll
      for (int r=0;r<4;r++)
        sv[n][r] = sa[n][r]*0.125f + bvv[n][r];

    // D: online softmax over this 64-key tile
    float tmax[4];
    #pragma unroll
    for (int r=0;r<4;r++)
      tmax[r] = fmaxf(fmaxf(sv[0][r],sv[1][r]), fmaxf(sv[2][r],sv[3][r]));
    #pragma unroll
    for (int off=1; off<16; off<<=1)
      #pragma unroll
      for (int r=0;r<4;r++)
        tmax[r] = fmaxf(tmax[r], __shfl_xor(tmax[r], off, 64));

    float alpha[4], rsum[4];
    #pragma unroll
    for (int r=0;r<4;r++){
      float mnew = fmaxf(m_run[r], tmax[r]);
      alpha[r] = __expf(m_run[r] - mnew);
      m_run[r] = mnew;
      rsum[r] = 0.0f;
    }
    #pragma unroll
    for (int n=0;n<4;n++)
      #pragma unroll
      for (int r=0;r<4;r++){
        float p = __expf(sv[n][r] - m_run[r]);
        sv[n][r] = p;
        rsum[r] += p;
      }
    #pragma unroll
    for (int off=1; off<16; off<<=1)
      #pragma unroll
      for (int r=0;r<4;r++)
        rsum[r] += __shfl_xor(rsum[r], off, 64);
    #pragma unroll
    for (int r=0;r<4;r++) l_run[r] = l_run[r]*alpha[r] + rsum[r];
    #pragma unroll
    for (int dg=0;dg<4;dg++)
      #pragma unroll
      for (int r=0;r<4;r++) o[dg][r] *= alpha[r];

    // E: P -> wave-private swizzled LDS -> A-frag; PV MFMA (swizzled V reads)
    u16* Pw = Ps + w*(16*64);
    #pragma unroll
    for (int n=0;n<4;n++)
      #pragma unroll
      for (int r=0;r<4;r++){
        const int prow = lhi*4 + r;
        Pw[prow*64 + ((n*16+lr) ^ ((prow&7)<<3))] = f2bf(sv[n][r]);
      }
    asm volatile("s_waitcnt lgkmcnt(0)" ::: "memory");
    __builtin_amdgcn_sched_barrier(0);

    #pragma unroll
    for (int sl=0; sl<2; ++sl){
      const int co = (sl*32 + lhi*8) ^ ((lr&7)<<3);
      short8 pf = *(const short8*)(Pw + lr*64 + co);
      #pragma unroll
      for (int dg=0; dg<4; dg++){
        short8 vf = *(const short8*)(&Vs[cur][(dg*16+lr)*64 + co]);
        o[dg] = __builtin_amdgcn_mfma_f32_16x16x32_bf16(pf, vf, o[dg], 0,0,0);
      }
    }

    // F: write staged regs for next tile (compiler inserts vmcnt waits)
    if (pre){
      const int nb = cur^1;
      *(short8*)(&Ks[nb][ldso0]) = kreg0;
      *(short8*)(&Ks[nb][ldso1]) = kreg1;
      *(short8*)(&Vs[nb][ldso0]) = vreg0;
      *(short8*)(&Vs[nb][ldso1]) = vreg1;
    }
    __syncthreads();
    cur ^= 1;
  }

  // ctx[b][s][h*64+d]  (bf16)
  #pragma unroll
  for (int dg=0; dg<4; dg++)
    #pragma unroll
    for (int r=0;r<4;r++){
      float val = o[dg][r] / l_run[r];
      int srow = q0 + w*16 + lhi*4 + r;
      ctx[((size_t)b*SQL + srow)*HID + h*64 + dg*16 + lr] = f2bf(val);
    }
}

extern "C" void kernel_launch(void* const* d_in, const int* in_sizes, int n_in,
                              void* d_out, int out_size, void* d_ws, size_t ws_size,
                              hipStream_t stream){
  const float* q  = (const float*)d_in[0];
  const float* k  = (const float*)d_in[1];
  const float* v  = (const float*)d_in[2];
  const float* ab = (const float*)d_in[3];
  const float* Wq = (const float*)d_in[4];
  const float* Wk = (const float*)d_in[5];
  const float* Wv = (const float*)d_in[6];
  const float* Wo = (const float*)d_in[7];
  const float* bq = (const float*)d_in[8];
  const float* bk = (const float*)d_in[9];
  const float* bv = (const float*)d_in[10];
  const float* bo = (const float*)d_in[11];

  char* ws = (char*)d_ws;
  const size_t MB = 1024*1024;
  u16* qb  = (u16*)(ws + 0*MB);    // 8 MB  [4096][1024] bf16
  u16* kb  = (u16*)(ws + 8*MB);
  u16* vb  = (u16*)(ws + 16*MB);
  u16* wqt = (u16*)(ws + 24*MB);   // 2 MB each, [N][K] bf16
  u16* wkt = (u16*)(ws + 26*MB);
  u16* wvt = (u16*)(ws + 28*MB);
  u16* wot = (u16*)(ws + 30*MB);
  u16* Qh  = (u16*)(ws + 32*MB);   // [B,H,S,D] bf16
  u16* Kh  = (u16*)(ws + 40*MB);   // [B,H,S,D]
  u16* Vt  = (u16*)(ws + 48*MB);   // [B,H,D,S]
  u16* ctx = (u16*)(ws + 56*MB);   // [B,S,HID] bf16

  dim3 cb(256);
  dim3 cg(MROWS*HID/4/256, 3);     // (4096, 3)
  cvt_bf16_3<<<cg, cb, 0, stream>>>(q, k, v, qb, kb, vb);

  dim3 tg(16,16,4);
  transpose_w4<<<tg, cb, 0, stream>>>(Wq, Wk, Wv, Wo, wqt, wkt, wvt, wot);

  dim3 gq(HID/128, MROWS/128, 3);  // (8, 32, 3)
  gemm_qkv<<<gq, cb, 0, stream>>>(qb, kb, vb, wqt, wkt, wvt, bq, bk, bv, Qh, Kh, Vt);

  dim3 ag(SQL/64, NB*NH);          // (16, 64)
  attn_fwd<<<ag, cb, 0, stream>>>(Qh, Kh, Vt, ab, ctx);

  dim3 gg(HID/128, MROWS/128);     // (8, 32)
  gemm_o<<<gg, cb, 0, stream>>>(ctx, wot, bo, (float*)d_out);
}